// Round 1
// baseline (314.521 us; speedup 1.0000x reference)
//
#include <hip/hip_runtime.h>
#include <math.h>

// B=4,S=4096 -> NTOK=16384; D=2048; E=8; R=16; K=2; SCALING=1
// Inputs fp32; d_out fp32: out[16384][2048] then probs[16384][8].
// ws layout (bf16/ushort): Wc[32][160][64] | Bm2[2048][128] | Hm[16384][128]
//   Wc: per-K-chunk packed W, rows 0-7 = gate hi, 8-15 = 0, 16-143 = A,
//       144-151 = gate lo, 152-159 = 0; granule-swizzled (g ^= row&7) so
//       global_load_lds (linear dest) + swizzled ds_read is conflict-free.
#define NTOK 16384
#define DIM  2048
#define NEXP 8
#define RANK 16

typedef unsigned short ushort_t;
typedef unsigned int   uint_t;
typedef __attribute__((ext_vector_type(8))) short bf16x8;
typedef __attribute__((ext_vector_type(4))) float f32x4;

__device__ __forceinline__ ushort_t f2bf(float f) {
  union { float f; uint_t u; } v; v.f = f;
  uint_t r = (v.u + 0x7FFFu + ((v.u >> 16) & 1u)) >> 16;
  return (ushort_t)r;
}
__device__ __forceinline__ float bf2f(ushort_t s) {
  union { uint_t u; float f; } v; v.u = ((uint_t)s) << 16;
  return v.f;
}

// async global -> LDS, 16B per lane; LDS dest = wave-uniform base + lane*16
__device__ __forceinline__ void gl_lds16(const ushort_t* g, ushort_t* l) {
  __builtin_amdgcn_global_load_lds(
      (const __attribute__((address_space(1))) unsigned int*)g,
      (__attribute__((address_space(3))) unsigned int*)l, 16, 0, 0);
}

// ---------------- K0: weight prep (fp32 -> bf16, pack + swizzle) ----------------
__global__ __launch_bounds__(256) void k0_prep(
    const float* __restrict__ gW, const float* __restrict__ A,
    const float* __restrict__ Bm,
    ushort_t* __restrict__ Wc, ushort_t* __restrict__ Bm2) {
  int b = blockIdx.x, t = threadIdx.x;
  if (b < 1280) {                       // Wc: 160 rows x 2048 cols = 327680 elems
    int idx = b * 256 + t;
    int r = idx >> 11, d = idx & 2047;
    float v;
    if (r < 8)        v = gW[r * 2048 + d];
    else if (r < 16)  v = 0.f;
    else if (r < 144) v = A[(size_t)(r - 16) * 2048 + d];
    else if (r < 152) { float g = gW[(r - 144) * 2048 + d]; v = g - bf2f(f2bf(g)); }
    else              v = 0.f;
    int ch = d >> 6, c = d & 63;
    int cs = ((((c >> 3) ^ (r & 7)) << 3) | (c & 7));     // granule XOR swizzle
    Wc[((size_t)ch * 160 + r) * 64 + cs] = f2bf(v);
  } else {                              // Bm2[2048][128]: Bm2[d][e*16+r]=Bm[e][d][r]
    int idx = (b - 1280) * 256 + t;     // 0..262143
    int dd = idx >> 7, c = idx & 127, e = c >> 4, rr = c & 15;
    Bm2[idx] = f2bf(Bm[((size_t)e * 2048 + dd) * 16 + rr]);
  }
}

// ---------------- K1: gate + h  (C[32 x 144] = x . W^T) ----------------
#define BKP 72   // x tiles stay reg-staged (need f2bf), padded: conflict-free

__global__ __launch_bounds__(256) void k1_gate_h(
    const float* __restrict__ x, const float* __restrict__ gate_b,
    const ushort_t* __restrict__ Wc,
    ushort_t* __restrict__ Hm, float* __restrict__ probs) {
  __shared__ __align__(16) ushort_t ws_w[2][160 * 64];   // double-buffered W chunk
  __shared__ __align__(16) ushort_t xs_hi[2][32][BKP];
  __shared__ __align__(16) ushort_t xs_lo[2][32][BKP];
  __shared__ float Cs[32][152];
  __shared__ int sel0s[32], sel1s[32];

  const int t = threadIdx.x;
  const int lane = t & 63, wave = t >> 6;
  const int l15 = lane & 15, q = lane >> 4;
  const int mt = wave & 1;        // M-tile (16 tokens)
  const int ng = wave >> 1;       // 0: N-tiles 0-3 (incl gate corr), 1: N-tiles 4-8
  const int ntiles = ng ? 5 : 4;
  const int tok0 = blockIdx.x * 32;

  f32x4 acc[5];
  #pragma unroll
  for (int i = 0; i < 5; ++i) acc[i] = (f32x4)0.f;

  const float4* xg = (const float4*)(x + (size_t)tok0 * DIM);
  const int xrow0 = t >> 4, xc4 = t & 15;

  float4 xv[2];

  auto load_x = [&](int ch) {                 // issue 2 float4 HBM loads -> regs
    xv[0] = xg[xrow0 * (DIM / 4) + ch * 16 + xc4];
    xv[1] = xg[(16 + xrow0) * (DIM / 4) + ch * 16 + xc4];
  };
  auto stage_w = [&](int ch, int buf) {       // 5x global_load_lds dwordx4 / thread
    const ushort_t* src = Wc + (size_t)ch * (160 * 64);
    #pragma unroll
    for (int i = 0; i < 5; ++i)
      gl_lds16(src + (size_t)(i * 256 + t) * 8,
               &ws_w[buf][(i * 256 + wave * 64) * 8]);
  };
  auto write_x = [&](int buf) {               // f2bf hi/lo split -> LDS
    #pragma unroll
    for (int i = 0; i < 2; ++i) {
      int row = xrow0 + i * 16;
      float vv[4] = {xv[i].x, xv[i].y, xv[i].z, xv[i].w};
      ushort_t h4[4], l4[4];
      #pragma unroll
      for (int j = 0; j < 4; ++j) {
        h4[j] = f2bf(vv[j]);
        l4[j] = f2bf(vv[j] - bf2f(h4[j]));
      }
      *(uint2*)&xs_hi[buf][row][xc4 * 4] = *(const uint2*)h4;
      *(uint2*)&xs_lo[buf][row][xc4 * 4] = *(const uint2*)l4;
    }
  };

  // prologue: fill buffer 0
  load_x(0);
  stage_w(0, 0);
  write_x(0);                 // compiler waits only the x loads (counted vmcnt)
  __syncthreads();            // drains gl-lds too

  for (int ch = 0; ch < 32; ++ch) {
    const int cur = ch & 1, nxt = cur ^ 1;
    if (ch < 31) { load_x(ch + 1); stage_w(ch + 1, nxt); }   // issue-early

    const ushort_t* wb = ws_w[cur];
    auto wfrag = [&](int r, int kkg) -> bf16x8 {
      int pos = (r << 3) + ((kkg + q) ^ (r & 7));            // un-swizzle on read
      return *(const bf16x8*)&wb[pos << 3];
    };

    #pragma unroll
    for (int kk = 0; kk < 64; kk += 32) {
      const int kkg = kk >> 3;
      bf16x8 ah = *(const bf16x8*)&xs_hi[cur][mt * 16 + l15][kk + q * 8];
      if (ng == 0) {
        bf16x8 al  = *(const bf16x8*)&xs_lo[cur][mt * 16 + l15][kk + q * 8];
        bf16x8 bgl = wfrag(144 + l15, kkg);
        bf16x8 b0  = wfrag(l15, kkg);
        acc[0] = __builtin_amdgcn_mfma_f32_16x16x32_bf16(ah, b0, acc[0], 0, 0, 0);
        acc[0] = __builtin_amdgcn_mfma_f32_16x16x32_bf16(al, b0, acc[0], 0, 0, 0);
        acc[0] = __builtin_amdgcn_mfma_f32_16x16x32_bf16(ah, bgl, acc[0], 0, 0, 0);
        #pragma unroll
        for (int nt = 1; nt < 4; ++nt) {
          bf16x8 b = wfrag(nt * 16 + l15, kkg);
          acc[nt] = __builtin_amdgcn_mfma_f32_16x16x32_bf16(ah, b, acc[nt], 0, 0, 0);
        }
      } else {
        #pragma unroll
        for (int nt = 0; nt < 5; ++nt) {
          bf16x8 b = wfrag(64 + nt * 16 + l15, kkg);
          acc[nt] = __builtin_amdgcn_mfma_f32_16x16x32_bf16(ah, b, acc[nt], 0, 0, 0);
        }
      }
    }

    if (ch < 31) write_x(nxt);    // write-late: x latency hidden under MFMA
    __syncthreads();              // single barrier per chunk (drains vm+lgkm)
  }

  // ---- write C tiles to LDS (col = lane&15, row = quad*4+reg) ----
  const int colbase = ng ? 64 : 0;
  #pragma unroll
  for (int i = 0; i < 5; ++i) {
    if (i < ntiles) {
      #pragma unroll
      for (int r = 0; r < 4; ++r)
        Cs[mt * 16 + q * 4 + r][colbase + i * 16 + l15] = acc[i][r];
    }
  }
  __syncthreads();

  // ---- softmax + top-2 per token ----
  if (t < 32) {
    int m = t;
    float lg[NEXP];
    #pragma unroll
    for (int e = 0; e < NEXP; ++e) lg[e] = Cs[m][e] + gate_b[e];
    float mx = lg[0];
    #pragma unroll
    for (int e = 1; e < NEXP; ++e) mx = fmaxf(mx, lg[e]);
    float ex[NEXP], s = 0.f;
    #pragma unroll
    for (int e = 0; e < NEXP; ++e) { ex[e] = __expf(lg[e] - mx); s += ex[e]; }
    float inv = 1.f / s;
    float4 p0 = make_float4(ex[0] * inv, ex[1] * inv, ex[2] * inv, ex[3] * inv);
    float4 p1 = make_float4(ex[4] * inv, ex[5] * inv, ex[6] * inv, ex[7] * inv);
    float* pp = probs + (size_t)(tok0 + m) * NEXP;
    *(float4*)pp = p0; *(float4*)(pp + 4) = p1;
    int i0 = 0;
    #pragma unroll
    for (int e = 1; e < NEXP; ++e) if (lg[e] > lg[i0]) i0 = e;
    int i1 = (i0 == 0) ? 1 : 0;
    #pragma unroll
    for (int e = 0; e < NEXP; ++e) if (e != i0 && lg[e] > lg[i1]) i1 = e;
    sel0s[m] = i0; sel1s[m] = i1;
  }
  __syncthreads();

  // ---- gelu + mask -> Hm bf16 ----
  {
    int m = t >> 3, e = t & 7;
    int on = (e == sel0s[m]) | (e == sel1s[m]);
    ushort_t ov[16];
    #pragma unroll
    for (int r = 0; r < RANK; ++r) {
      float v = Cs[m][16 + e * 16 + r];
      float g = on ? (0.5f * v * (1.f + erff(v * 0.70710678118654752f))) : 0.f;
      ov[r] = f2bf(g);
    }
    ushort_t* hp = Hm + ((size_t)(tok0 + m) * 128 + e * 16);
    *(uint4*)hp       = *(const uint4*)&ov[0];
    *(uint4*)(hp + 8) = *(const uint4*)&ov[8];
  }
}

// ---------------- K2: out[16384][2048] = Hm[.,128] . Bm2[128,.] ----------------
// Block = 1 wave, 32 tokens (2 M-tiles) x 256 cols (16 N-tiles).
// 4096 blocks -> 16 waves/CU; fully unrolled with double-buffered B prefetch.
__global__ __launch_bounds__(64) void k2_combine(
    const ushort_t* __restrict__ Hm, const ushort_t* __restrict__ Bm2,
    float* __restrict__ out) {
  const int lane = threadIdx.x;
  const int l15 = lane & 15, q = lane >> 4;
  const int t0 = blockIdx.x * 32;
  const int nb = blockIdx.y * 256;

  // A-frags: 2 M-tiles x 4 k-steps, in registers for the whole block
  bf16x8 a[2][4];
  #pragma unroll
  for (int mt = 0; mt < 2; ++mt)
    #pragma unroll
    for (int kk = 0; kk < 4; ++kk)
      a[mt][kk] = *(const bf16x8*)&Hm[(size_t)(t0 + mt * 16 + l15) * 128 + kk * 32 + q * 8];

  const ushort_t* bp = Bm2 + (size_t)(nb + l15) * 128 + q * 8;

  auto loadB = [&](bf16x8* dst, int i) {
    #pragma unroll
    for (int k = 0; k < 4; ++k)
      dst[k] = *(const bf16x8*)(bp + (size_t)i * 2048 + k * 32);   // 16 rows x 128
  };
  auto comp = [&](const bf16x8* bb, int i) {
    #pragma unroll
    for (int mt = 0; mt < 2; ++mt) {
      f32x4 c = (f32x4)0.f;
      #pragma unroll
      for (int k = 0; k < 4; ++k)
        c = __builtin_amdgcn_mfma_f32_16x16x32_bf16(a[mt][k], bb[k], c, 0, 0, 0);
      #pragma unroll
      for (int r = 0; r < 4; ++r)
        out[(size_t)(t0 + mt * 16 + q * 4 + r) * DIM + nb + i * 16 + l15] = c[r];
    }
  };

  bf16x8 bA[4], bB[4];
  loadB(bA, 0);
  #pragma unroll
  for (int ii = 0; ii < 8; ++ii) {          // static indices only (no scratch)
    loadB(bB, 2 * ii + 1);
    comp(bA, 2 * ii);
    if (ii < 7) loadB(bA, 2 * ii + 2);
    comp(bB, 2 * ii + 1);
  }
}

extern "C" void kernel_launch(void* const* d_in, const int* in_sizes, int n_in,
                              void* d_out, int out_size, void* d_ws, size_t ws_size,
                              hipStream_t stream) {
  const float* x      = (const float*)d_in[0];
  const float* gate_W = (const float*)d_in[1];
  const float* gate_b = (const float*)d_in[2];
  const float* A      = (const float*)d_in[3];
  const float* Bm     = (const float*)d_in[4];

  float* out   = (float*)d_out;                 // [NTOK][DIM]
  float* probs = out + (size_t)NTOK * DIM;      // [NTOK][NEXP]

  ushort_t* Wc  = (ushort_t*)d_ws;              // [32][160][64]
  ushort_t* Bm2 = Wc + 32 * 160 * 64;           // [2048][128]
  ushort_t* Hm  = Bm2 + 2048 * 128;             // [16384][128]

  k0_prep<<<dim3(2304), dim3(256), 0, stream>>>(gate_W, A, Bm, Wc, Bm2);
  k1_gate_h<<<dim3(NTOK / 32), dim3(256), 0, stream>>>(x, gate_b, Wc, Hm, probs);
  k2_combine<<<dim3(NTOK / 32, DIM / 256), dim3(64), 0, stream>>>(Hm, Bm2, out);
}

// Round 3
// 275.887 us; speedup vs baseline: 1.1400x; 1.1400x over previous
//
#include <hip/hip_runtime.h>
#include <math.h>

// B=4,S=4096 -> NTOK=16384; D=2048; E=8; R=16; K=2; SCALING=1
// Inputs fp32; d_out fp32: out[16384][2048] then probs[16384][8].
// ws layout (bf16/ushort): Wc[32][160][64] | Bm2[2048][128]
//   Wc: per-K-chunk packed W, rows 0-7 = gate hi, 8-15 = 0, 16-143 = A,
//       144-151 = gate lo, 152-159 = 0; granule-swizzled (g ^= row&7) so
//       global_load_lds (linear dest) + swizzled ds_read is conflict-free.
// Fused kernel: gate+h (MFMA vs Wc) -> softmax/top2 -> gelu+mask into LDS
// -> combine out[32][2048] = Hm_lds . Bm2^T directly (no Hm round-trip,
//    no second dispatch). Combine uses swapped-operand MFMA so each lane
//    holds 4 consecutive columns -> float4 stores.
#define NTOK 16384
#define DIM  2048
#define NEXP 8
#define RANK 16

typedef unsigned short ushort_t;
typedef unsigned int   uint_t;
typedef __attribute__((ext_vector_type(8))) short bf16x8;
typedef __attribute__((ext_vector_type(4))) float f32x4;

__device__ __forceinline__ ushort_t f2bf(float f) {
  union { float f; uint_t u; } v; v.f = f;
  uint_t r = (v.u + 0x7FFFu + ((v.u >> 16) & 1u)) >> 16;
  return (ushort_t)r;
}
__device__ __forceinline__ float bf2f(ushort_t s) {
  union { uint_t u; float f; } v; v.u = ((uint_t)s) << 16;
  return v.f;
}

// async global -> LDS, 16B per lane; LDS dest = wave-uniform base + lane*16
__device__ __forceinline__ void gl_lds16(const ushort_t* g, ushort_t* l) {
  __builtin_amdgcn_global_load_lds(
      (const __attribute__((address_space(1))) unsigned int*)g,
      (__attribute__((address_space(3))) unsigned int*)l, 16, 0, 0);
}

// ---------------- K0: weight prep (fp32 -> bf16, pack + swizzle) ----------------
__global__ __launch_bounds__(256) void k0_prep(
    const float* __restrict__ gW, const float* __restrict__ A,
    const float* __restrict__ Bm,
    ushort_t* __restrict__ Wc, ushort_t* __restrict__ Bm2) {
  int b = blockIdx.x, t = threadIdx.x;
  if (b < 1280) {                       // Wc: 160 rows x 2048 cols = 327680 elems
    int idx = b * 256 + t;
    int r = idx >> 11, d = idx & 2047;
    float v;
    if (r < 8)        v = gW[r * 2048 + d];
    else if (r < 16)  v = 0.f;
    else if (r < 144) v = A[(size_t)(r - 16) * 2048 + d];
    else if (r < 152) { float g = gW[(r - 144) * 2048 + d]; v = g - bf2f(f2bf(g)); }
    else              v = 0.f;
    int ch = d >> 6, c = d & 63;
    int cs = ((((c >> 3) ^ (r & 7)) << 3) | (c & 7));     // granule XOR swizzle
    Wc[((size_t)ch * 160 + r) * 64 + cs] = f2bf(v);
  } else {                              // Bm2[2048][128]: Bm2[d][e*16+r]=Bm[e][d][r]
    int idx = (b - 1280) * 256 + t;     // 0..262143
    int dd = idx >> 7, c = idx & 127, e = c >> 4, rr = c & 15;
    Bm2[idx] = f2bf(Bm[((size_t)e * 2048 + dd) * 16 + rr]);
  }
}

// ---------------- K1: fused gate + h + combine ----------------
#define BKP 72   // x tiles stay reg-staged (need f2bf), padded: conflict-free

__global__ __launch_bounds__(256) void k1_fused(
    const float* __restrict__ x, const float* __restrict__ gate_b,
    const ushort_t* __restrict__ Wc, const ushort_t* __restrict__ Bm2,
    float* __restrict__ out, float* __restrict__ probs) {
  __shared__ __align__(16) ushort_t ws_w[2][160 * 64];   // double-buffered W chunk
  __shared__ __align__(16) ushort_t xs_hi[2][32][BKP];
  __shared__ __align__(16) ushort_t xs_lo[2][32][BKP];
  __shared__ float Cs[32][152];
  __shared__ int sel0s[32], sel1s[32];
  // hm_s[32][128] (granule-swizzled) overlays ws_w, which is dead post K-loop
  ushort_t* hm_s = &ws_w[0][0];

  const int t = threadIdx.x;
  const int lane = t & 63, wave = t >> 6;
  const int l15 = lane & 15, q = lane >> 4;
  const int mt = wave & 1;        // M-tile (16 tokens)
  const int ng = wave >> 1;       // 0: N-tiles 0-3 (incl gate corr), 1: N-tiles 4-8
  const int ntiles = ng ? 5 : 4;
  const int tok0 = blockIdx.x * 32;

  f32x4 acc[5];
  #pragma unroll
  for (int i = 0; i < 5; ++i) acc[i] = (f32x4)0.f;

  const float4* xg = (const float4*)(x + (size_t)tok0 * DIM);
  const int xrow0 = t >> 4, xc4 = t & 15;

  float4 xv[2];

  auto load_x = [&](int ch) {                 // issue 2 float4 HBM loads -> regs
    xv[0] = xg[xrow0 * (DIM / 4) + ch * 16 + xc4];
    xv[1] = xg[(16 + xrow0) * (DIM / 4) + ch * 16 + xc4];
  };
  auto stage_w = [&](int ch, int buf) {       // 5x global_load_lds dwordx4 / thread
    const ushort_t* src = Wc + (size_t)ch * (160 * 64);
    #pragma unroll
    for (int i = 0; i < 5; ++i)
      gl_lds16(src + (size_t)(i * 256 + t) * 8,
               &ws_w[buf][(i * 256 + wave * 64) * 8]);
  };
  auto write_x = [&](int buf) {               // f2bf hi/lo split -> LDS
    #pragma unroll
    for (int i = 0; i < 2; ++i) {
      int row = xrow0 + i * 16;
      float vv[4] = {xv[i].x, xv[i].y, xv[i].z, xv[i].w};
      ushort_t h4[4], l4[4];
      #pragma unroll
      for (int j = 0; j < 4; ++j) {
        h4[j] = f2bf(vv[j]);
        l4[j] = f2bf(vv[j] - bf2f(h4[j]));
      }
      *(uint2*)&xs_hi[buf][row][xc4 * 4] = *(const uint2*)h4;
      *(uint2*)&xs_lo[buf][row][xc4 * 4] = *(const uint2*)l4;
    }
  };

  // prologue: fill buffer 0
  load_x(0);
  stage_w(0, 0);
  write_x(0);
  __syncthreads();            // drains gl-lds too

  for (int ch = 0; ch < 32; ++ch) {
    const int cur = ch & 1, nxt = cur ^ 1;
    if (ch < 31) { load_x(ch + 1); stage_w(ch + 1, nxt); }   // issue-early

    const ushort_t* wb = ws_w[cur];
    auto wfrag = [&](int r, int kkg) -> bf16x8 {
      int pos = (r << 3) + ((kkg + q) ^ (r & 7));            // un-swizzle on read
      return *(const bf16x8*)&wb[pos << 3];
    };

    #pragma unroll
    for (int kk = 0; kk < 64; kk += 32) {
      const int kkg = kk >> 3;
      bf16x8 ah = *(const bf16x8*)&xs_hi[cur][mt * 16 + l15][kk + q * 8];
      if (ng == 0) {
        bf16x8 al  = *(const bf16x8*)&xs_lo[cur][mt * 16 + l15][kk + q * 8];
        bf16x8 bgl = wfrag(144 + l15, kkg);
        bf16x8 b0  = wfrag(l15, kkg);
        acc[0] = __builtin_amdgcn_mfma_f32_16x16x32_bf16(ah, b0, acc[0], 0, 0, 0);
        acc[0] = __builtin_amdgcn_mfma_f32_16x16x32_bf16(al, b0, acc[0], 0, 0, 0);
        acc[0] = __builtin_amdgcn_mfma_f32_16x16x32_bf16(ah, bgl, acc[0], 0, 0, 0);
        #pragma unroll
        for (int nt = 1; nt < 4; ++nt) {
          bf16x8 b = wfrag(nt * 16 + l15, kkg);
          acc[nt] = __builtin_amdgcn_mfma_f32_16x16x32_bf16(ah, b, acc[nt], 0, 0, 0);
        }
      } else {
        #pragma unroll
        for (int nt = 0; nt < 5; ++nt) {
          bf16x8 b = wfrag(64 + nt * 16 + l15, kkg);
          acc[nt] = __builtin_amdgcn_mfma_f32_16x16x32_bf16(ah, b, acc[nt], 0, 0, 0);
        }
      }
    }

    if (ch < 31) write_x(nxt);    // write-late: x latency hidden under MFMA
    __syncthreads();              // single barrier per chunk (drains vm+lgkm)
  }

  // ---- write C tiles to LDS (col = lane&15, row = quad*4+reg) ----
  const int colbase = ng ? 64 : 0;
  #pragma unroll
  for (int i = 0; i < 5; ++i) {
    if (i < ntiles) {
      #pragma unroll
      for (int r = 0; r < 4; ++r)
        Cs[mt * 16 + q * 4 + r][colbase + i * 16 + l15] = acc[i][r];
    }
  }
  __syncthreads();

  // ---- softmax + top-2 per token ----
  if (t < 32) {
    int m = t;
    float lg[NEXP];
    #pragma unroll
    for (int e = 0; e < NEXP; ++e) lg[e] = Cs[m][e] + gate_b[e];
    float mx = lg[0];
    #pragma unroll
    for (int e = 1; e < NEXP; ++e) mx = fmaxf(mx, lg[e]);
    float ex[NEXP], s = 0.f;
    #pragma unroll
    for (int e = 0; e < NEXP; ++e) { ex[e] = __expf(lg[e] - mx); s += ex[e]; }
    float inv = 1.f / s;
    float4 p0 = make_float4(ex[0] * inv, ex[1] * inv, ex[2] * inv, ex[3] * inv);
    float4 p1 = make_float4(ex[4] * inv, ex[5] * inv, ex[6] * inv, ex[7] * inv);
    float* pp = probs + (size_t)(tok0 + m) * NEXP;
    *(float4*)pp = p0; *(float4*)(pp + 4) = p1;
    int i0 = 0;
    #pragma unroll
    for (int e = 1; e < NEXP; ++e) if (lg[e] > lg[i0]) i0 = e;
    int i1 = (i0 == 0) ? 1 : 0;
    #pragma unroll
    for (int e = 0; e < NEXP; ++e) if (e != i0 && lg[e] > lg[i1]) i1 = e;
    sel0s[m] = i0; sel1s[m] = i1;
  }
  __syncthreads();

  // ---- gelu + mask -> hm_s (LDS, granule-XOR-swizzled rows of 128) ----
  {
    int m = t >> 3, e = t & 7;
    int on = (e == sel0s[m]) | (e == sel1s[m]);
    ushort_t ov[16];
    #pragma unroll
    for (int r = 0; r < RANK; ++r) {
      float v = Cs[m][16 + e * 16 + r];
      float g = on ? (0.5f * v * (1.f + erff(v * 0.70710678118654752f))) : 0.f;
      ov[r] = f2bf(g);
    }
    int g0 = (2 * e) ^ (m & 7), g1 = (2 * e + 1) ^ (m & 7);
    *(uint4*)&hm_s[m * 128 + g0 * 8] = *(const uint4*)&ov[0];
    *(uint4*)&hm_s[m * 128 + g1 * 8] = *(const uint4*)&ov[8];
  }
  __syncthreads();

  // ---- combine: out[32][2048] = Hm_lds . Bm2^T; wave w owns cols w*512.. ----
  {
    bf16x8 af[2][4];
    #pragma unroll
    for (int m2 = 0; m2 < 2; ++m2) {
      int tok = m2 * 16 + l15;
      #pragma unroll
      for (int kk = 0; kk < 4; ++kk)
        af[m2][kk] = *(const bf16x8*)&hm_s[tok * 128 + (((kk * 4 + q) ^ (tok & 7)) << 3)];
    }

    const int ncol0 = wave * 512;
    const ushort_t* bp = Bm2 + (size_t)(ncol0 + l15) * 128 + q * 8;

    auto loadB = [&](bf16x8* dst, int i) {
      #pragma unroll
      for (int k = 0; k < 4; ++k)
        dst[k] = *(const bf16x8*)(bp + (size_t)i * 2048 + k * 32);   // 16 rows/tile
    };
    auto comp = [&](const bf16x8* bb, int i) {
      #pragma unroll
      for (int m2 = 0; m2 < 2; ++m2) {
        f32x4 c = (f32x4)0.f;
        #pragma unroll
        for (int k = 0; k < 4; ++k)   // swapped operands -> transposed C layout
          c = __builtin_amdgcn_mfma_f32_16x16x32_bf16(bb[k], af[m2][k], c, 0, 0, 0);
        // lane holds out[tok0+m2*16+l15][ncol0+i*16+q*4 .. +3] -> float4 store
        *(f32x4*)&out[(size_t)(tok0 + m2 * 16 + l15) * DIM + ncol0 + i * 16 + q * 4] = c;
      }
    };

    bf16x8 bA[4], bB[4];
    loadB(bA, 0);
    #pragma unroll
    for (int ii = 0; ii < 16; ++ii) {        // static indices only (no scratch)
      loadB(bB, 2 * ii + 1);
      comp(bA, 2 * ii);
      if (ii < 15) loadB(bA, 2 * ii + 2);
      comp(bB, 2 * ii + 1);
    }
  }
}

extern "C" void kernel_launch(void* const* d_in, const int* in_sizes, int n_in,
                              void* d_out, int out_size, void* d_ws, size_t ws_size,
                              hipStream_t stream) {
  const float* x      = (const float*)d_in[0];
  const float* gate_W = (const float*)d_in[1];
  const float* gate_b = (const float*)d_in[2];
  const float* A      = (const float*)d_in[3];
  const float* Bm     = (const float*)d_in[4];

  float* out   = (float*)d_out;                 // [NTOK][DIM]
  float* probs = out + (size_t)NTOK * DIM;      // [NTOK][NEXP]

  ushort_t* Wc  = (ushort_t*)d_ws;              // [32][160][64]
  ushort_t* Bm2 = Wc + 32 * 160 * 64;           // [2048][128]

  k0_prep<<<dim3(2304), dim3(256), 0, stream>>>(gate_W, A, Bm, Wc, Bm2);
  k1_fused<<<dim3(NTOK / 32), dim3(256), 0, stream>>>(x, gate_b, Wc, Bm2, out, probs);
}